// Round 4
// baseline (367.169 us; speedup 1.0000x reference)
//
#include <hip/hip_runtime.h>
#include <hip/hip_fp16.h>

#define T_DIM 2048
#define H_DIM 256
#define B_DIM 64

/* fan kernel chunking */
#define FCH 64                /* t per fan block */
#define FNCH (T_DIM / FCH)    /* 32 chunks per batch row */
#define FNCB (B_DIM * FNCH)   /* 2048 fan blocks = 8 blocks/CU = 8 waves/SIMD */

/* epilogue chunking */
#define ECH 64
#define ENCH (T_DIM / ECH)    /* 32 */
#define ENCB (B_DIM * ENCH)   /* 2048 */

#define EPS_F 1e-4f
#define R1C (1.0f / 1.0001f)
#define R2C (1.0f / 2.0001f)

// mu and inv-sd (= 1/max(sqrt(var),EPS)) from window sums.
__device__ __forceinline__ void win_stats(float s1, float s2, float inv_w, float inv_wm1,
                                          float& mu, float& isd) {
    mu = s1 * inv_w;
    float var = fmaxf((s2 - s1 * s1 * inv_w) * inv_wm1, 0.0f);
    // 1/max(sqrt(var),1e-4) == min(rsqrt(var), 1e4); rsqrt(0)=inf -> 1e4. Matches ref.
    isd = fminf(rsqrtf(var), 1e4f);
}

// FAN for one FCH-t chunk of one (b, h) column.
// Delay handling (R2: reloading all delays puts L2 latency on the critical path;
// R3: hist[16]+reload = 68 VGPR, one reg over the 64 occupancy step):
//   - FULL 64-step unroll -> all ring indices compile-time -> ring of EXACTLY 10
//     slots serves delay-5 (slot (r+5)%10) and delay-10 (slot r%10, read before
//     overwrite). 10 VGPR instead of 16.
//   - delay 20 re-loaded from cache (sequential stream, hoistable by scheduler).
// MODE 0: stash fan as __half2 t-pairs (layout [t/2][h][2]); MODE 1: fp32 to d_out.
template <int MODE, bool FIRST>
__device__ __forceinline__ void run_chunk(
    const float* __restrict__ xbh, __half2* __restrict__ s2bh, float* __restrict__ s32bh,
    int t0, float al0, float al1, float al2,
    float& ls1, float& ls2,
    float mu5i, float isd5i, float mu10i, float isd10i, float mu20i, float isd20i) {

    float s1_5 = 0.f, s2_5 = 0.f, s1_10 = 0.f, s2_10 = 0.f, s1_20 = 0.f, s2_20 = 0.f;
    float ring[10];
    float fprev = 0.0f;

    if (FIRST) {
#pragma unroll
        for (int j = 0; j < 10; ++j) ring[j] = 0.0f;
    } else {
        // Warm-up: window sums covering [t0-20, t0). Value at relative position
        // r = -j lives in slot (10 - j) % 10 (j = 1..10).
#pragma unroll
        for (int j = 1; j <= 20; ++j) {
            float v = xbh[(t0 - j) * H_DIM];
            s1_20 += v; s2_20 += v * v;
            if (j <= 10) { s1_10 += v; s2_10 += v * v; ring[(10 - j) % 10] = v; }
            if (j <= 5)  { s1_5  += v; s2_5  += v * v; }
        }
    }

#pragma unroll
    for (int r = 0; r < FCH; ++r) {
        const int t = t0 + r;           // r is compile-time (full unroll)
        const float v = xbh[t * H_DIM];
        float o20 = 0.0f;
        if (!FIRST || r >= 20) o20 = xbh[(t - 20) * H_DIM];
        const float o5  = ring[(r + 5) % 10];   // value at r-5
        const float o10 = ring[r % 10];         // value at r-10 (read before write)
        ring[r % 10] = v;

        s1_5  += v; s2_5  += v * v;
        s1_10 += v; s2_10 += v * v;
        s1_20 += v; s2_20 += v * v;
        if (!FIRST || r >= 5)  { s1_5  -= o5;  s2_5  -= o5  * o5;  }
        if (!FIRST || r >= 10) { s1_10 -= o10; s2_10 -= o10 * o10; }
        if (!FIRST || r >= 20) { s1_20 -= o20; s2_20 -= o20 * o20; }

        float mu, isd, fan = 0.0f;
        if (!FIRST || r >= 4)  win_stats(s1_5,  s2_5,  0.2f,  0.25f,      mu, isd);
        else { mu = mu5i;  isd = isd5i; }
        fan += (v - mu) * isd * al0;
        if (!FIRST || r >= 9)  win_stats(s1_10, s2_10, 0.1f,  1.f / 9.f,  mu, isd);
        else { mu = mu10i; isd = isd10i; }
        fan += (v - mu) * isd * al1;
        if (!FIRST || r >= 19) win_stats(s1_20, s2_20, 0.05f, 1.f / 19.f, mu, isd);
        else { mu = mu20i; isd = isd20i; }
        fan += (v - mu) * isd * al2;

        ls1 += fan; ls2 += fan * fan;
        if (MODE == 0) {
            if (r & 1) s2bh[(size_t)(t >> 1) * H_DIM] =
                           __halves2half2(__float2half(fprev), __float2half(fan));
            else       fprev = fan;
        } else {
            s32bh[t * H_DIM] = fan;
        }
    }
}

// REGISTER NOTE: target <=64 VGPR for 8 waves/SIMD (occupancy steps at 64/128/256).
// ring[10] + 6 sums + misc ~= 60 live. Plain __launch_bounds__(256): if allocation
// exceeds 64 we degrade to 7 waves/SIMD rather than spill via a forced cap
// (forced caps spilled catastrophically in earlier rounds).
template <int MODE>
__global__ __launch_bounds__(256)
void fan_kernel(const float* __restrict__ x, const float* __restrict__ alpha,
                float* __restrict__ part, __half* __restrict__ stash16,
                float* __restrict__ stash32) {
    // XCD-aware bijective swizzle (FNCB = 2048 = 8*256).
    const int blk = (blockIdx.x & 7) * (FNCB / 8) + (blockIdx.x >> 3);
    const int b = blk / FNCH;
    const int c = blk % FNCH;
    const int h = threadIdx.x;
    const int t0 = c * FCH;
    const size_t base = (size_t)b * T_DIM * H_DIM + h;
    const float* xbh = x + base;
    __half2* s2bh = (MODE == 0)
        ? (__half2*)stash16 + (size_t)b * (T_DIM / 2) * H_DIM + h : nullptr;
    float* s32bh = (MODE == 1) ? stash32 + base : nullptr;

    // softmax over alpha[h][0..2]
    const float a0 = alpha[h * 3 + 0], a1 = alpha[h * 3 + 1], a2 = alpha[h * 3 + 2];
    const float mx = fmaxf(a0, fmaxf(a1, a2));
    const float e0 = __expf(a0 - mx), e1 = __expf(a1 - mx), e2 = __expf(a2 - mx);
    const float einv = 1.0f / (e0 + e1 + e2);
    const float al0 = e0 * einv, al1 = e1 * einv, al2 = e2 * einv;

    float ls1 = 0.0f, ls2 = 0.0f;

    if (c == 0) {
        // Edge stats: windows [0,w) used for t < w-1 (reference edge-pad semantics).
        float mu5i, isd5i, mu10i, isd10i, mu20i, isd20i;
        float c1 = 0.f, c2 = 0.f;
#pragma unroll
        for (int j = 0; j < 20; ++j) {
            float v = xbh[j * H_DIM];
            c1 += v; c2 += v * v;
            if (j == 4)  win_stats(c1, c2, 0.2f,  0.25f,      mu5i,  isd5i);
            if (j == 9)  win_stats(c1, c2, 0.1f,  1.f / 9.f,  mu10i, isd10i);
            if (j == 19) win_stats(c1, c2, 0.05f, 1.f / 19.f, mu20i, isd20i);
        }
        run_chunk<MODE, true>(xbh, s2bh, s32bh, t0, al0, al1, al2, ls1, ls2,
                              mu5i, isd5i, mu10i, isd10i, mu20i, isd20i);
    } else {
        run_chunk<MODE, false>(xbh, s2bh, s32bh, t0, al0, al1, al2, ls1, ls2,
                               0.f, 0.f, 0.f, 0.f, 0.f, 0.f);
    }

    part[(0 * FNCB + blk) * H_DIM + h] = ls1;
    part[(1 * FNCB + blk) * H_DIM + h] = ls2;
}

// 32 blocks: (slice k = blk>>4, 1/16th g = blk&15). NO atomics: writes partial
// sums to part2[64][256]: rows [0..15]=S1 slice0, [16..31]=S2 slice0,
// [32..47]=S1 slice1, [48..63]=S2 slice1. Epilogue finishes the reduction.
__global__ __launch_bounds__(256)
void reduce_kernel(const float* __restrict__ part, float* __restrict__ part2) {
    const int h = threadIdx.x;
    const int k = blockIdx.x >> 4;     // slice 0/1
    const int g = blockIdx.x & 15;
    float a1 = 0.f, a2 = 0.f;
    for (int i = 0; i < FNCB / 16; ++i) {
        const int blk = g * (FNCB / 16) + i;
        const int c = blk % FNCH;
        const bool member = (k == 0) ? (c < 24) : (c >= 16);
        if (member) {
            a1 += part[(0 * FNCB + blk) * H_DIM + h];
            a2 += part[(1 * FNCB + blk) * H_DIM + h];
        }
    }
    part2[((2 * k + 0) * 16 + g) * H_DIM + h] = a1;
    part2[((2 * k + 1) * 16 + g) * H_DIM + h] = a2;
}

// Epilogue with inlined finalize: each block sums the 16 partials per category
// (64 KB, L2-hot across all blocks), computes per-h affine coefs into LDS, then
// streams out = x + fan*A + B. HALF path reads the paired __half2 stash: one
// 16 B read serves two t.
template <bool HALF>
__global__ __launch_bounds__(256)
void epilogue_kernel(const float* __restrict__ x, const void* __restrict__ fanp,
                     const float* __restrict__ part2, const float* __restrict__ gamma,
                     const float* __restrict__ beta, float* __restrict__ out) {
    __shared__ __align__(16) float cf[4][H_DIM];
    const int tid = threadIdx.x;

    // ---- inline finalize (per-h, thread tid = h) ----
    {
        float S10 = 0.f, S20 = 0.f, S11 = 0.f, S21 = 0.f;
#pragma unroll
        for (int g = 0; g < 16; ++g) {
            S10 += part2[(0 * 16 + g) * H_DIM + tid];
            S20 += part2[(1 * 16 + g) * H_DIM + tid];
            S11 += part2[(2 * 16 + g) * H_DIM + tid];
            S21 += part2[(3 * 16 + g) * H_DIM + tid];
        }
        const float N0 = 64.0f * 1536.0f, N1 = 64.0f * 1024.0f;
        float mu0 = S10 / N0;
        float v0 = fmaxf((S20 - S10 * S10 / N0) / (N0 - 1.0f), 0.0f);
        float isd0 = 1.0f / fmaxf(sqrtf(v0), EPS_F);
        float mu1 = S11 / N1;
        float v1 = fmaxf((S21 - S11 * S11 / N1) / (N1 - 1.0f), 0.0f);
        float isd1 = 1.0f / fmaxf(sqrtf(v1), EPS_F);
        float A0 = isd0 * gamma[0 * H_DIM + tid];
        float A1 = isd1 * gamma[1 * H_DIM + tid];
        cf[0][tid] = A0;
        cf[1][tid] = beta[0 * H_DIM + tid] - mu0 * A0;
        cf[2][tid] = A1;
        cf[3][tid] = beta[1 * H_DIM + tid] - mu1 * A1;
    }
    __syncthreads();

    const int blk = blockIdx.x;
    const int b = blk / ENCH;
    const int c = blk % ENCH;
    const int wave = tid >> 6;
    const int lane = tid & 63;
    const int h4 = lane * 4;

    float4 A0 = *(const float4*)&cf[0][h4];
    float4 B0 = *(const float4*)&cf[1][h4];
    float4 A1 = *(const float4*)&cf[2][h4];
    float4 B1 = *(const float4*)&cf[3][h4];
    float4 A, Bv;
    if (c < 16) {
        A  = make_float4(A0.x * R1C, A0.y * R1C, A0.z * R1C, A0.w * R1C);
        Bv = make_float4(B0.x * R1C, B0.y * R1C, B0.z * R1C, B0.w * R1C);
    } else if (c >= 24) {
        A  = make_float4(A1.x * R1C, A1.y * R1C, A1.z * R1C, A1.w * R1C);
        Bv = make_float4(B1.x * R1C, B1.y * R1C, B1.z * R1C, B1.w * R1C);
    } else {
        A  = make_float4((A0.x + A1.x) * R2C, (A0.y + A1.y) * R2C, (A0.z + A1.z) * R2C, (A0.w + A1.w) * R2C);
        Bv = make_float4((B0.x + B1.x) * R2C, (B0.y + B1.y) * R2C, (B0.z + B1.z) * R2C, (B0.w + B1.w) * R2C);
    }

    const int tbase = c * ECH + wave * 16;
    if (HALF) {
        const __half2* s2 = (const __half2*)fanp + (size_t)b * (T_DIM / 2) * H_DIM + h4;
#pragma unroll 2
        for (int p = 0; p < 8; ++p) {
            const int t = tbase + 2 * p;
            const size_t xi = ((size_t)b * T_DIM + t) * H_DIM + h4;
            float4 x0 = *(const float4*)&x[xi];
            float4 x1 = *(const float4*)&x[xi + H_DIM];
            float4 sv = *(const float4*)(s2 + (size_t)(t >> 1) * H_DIM);
            __half2 q0 = *reinterpret_cast<const __half2*>(&sv.x);
            __half2 q1 = *reinterpret_cast<const __half2*>(&sv.y);
            __half2 q2 = *reinterpret_cast<const __half2*>(&sv.z);
            __half2 q3 = *reinterpret_cast<const __half2*>(&sv.w);
            float4 o0, o1;
            o0.x = x0.x + fmaf(__low2float(q0),  A.x, Bv.x);
            o0.y = x0.y + fmaf(__low2float(q1),  A.y, Bv.y);
            o0.z = x0.z + fmaf(__low2float(q2),  A.z, Bv.z);
            o0.w = x0.w + fmaf(__low2float(q3),  A.w, Bv.w);
            o1.x = x1.x + fmaf(__high2float(q0), A.x, Bv.x);
            o1.y = x1.y + fmaf(__high2float(q1), A.y, Bv.y);
            o1.z = x1.z + fmaf(__high2float(q2), A.z, Bv.z);
            o1.w = x1.w + fmaf(__high2float(q3), A.w, Bv.w);
            *(float4*)&out[xi] = o0;
            *(float4*)&out[xi + H_DIM] = o1;
        }
    } else {
#pragma unroll 4
        for (int i = 0; i < 16; ++i) {
            const size_t idx = ((size_t)b * T_DIM + tbase + i) * H_DIM + h4;
            float4 xv = *(const float4*)&x[idx];
            float4 fv = *(const float4*)&((const float*)fanp)[idx];
            float4 o;
            o.x = xv.x + fmaf(fv.x, A.x, Bv.x);
            o.y = xv.y + fmaf(fv.y, A.y, Bv.y);
            o.z = xv.z + fmaf(fv.z, A.z, Bv.z);
            o.w = xv.w + fmaf(fv.w, A.w, Bv.w);
            *(float4*)&out[idx] = o;
        }
    }
}

extern "C" void kernel_launch(void* const* d_in, const int* in_sizes, int n_in,
                              void* d_out, int out_size, void* d_ws, size_t ws_size,
                              hipStream_t stream) {
    const float* x     = (const float*)d_in[0];
    const float* alpha = (const float*)d_in[1];
    const float* gamma = (const float*)d_in[2];
    const float* beta  = (const float*)d_in[3];
    float* out  = (float*)d_out;

    float* part  = (float*)d_ws;                         // 2*FNCB*H floats = 4 MB
    float* part2 = part + 2 * FNCB * H_DIM;              // 64*H floats = 64 KB
    __half* stash16 = (__half*)(part2 + 64 * H_DIM);     // B*T*H halves = 67 MB
    const size_t need = (size_t)(2 * FNCB * H_DIM + 64 * H_DIM) * 4
                      + (size_t)B_DIM * T_DIM * H_DIM * 2;
    const bool half_path = (ws_size >= need);            // constant per process -> graph-safe

    if (half_path) {
        fan_kernel<0><<<FNCB, H_DIM, 0, stream>>>(x, alpha, part, stash16, nullptr);
    } else {
        // Fallback: stash fp32 fan in d_out; epilogue overwrites it in place.
        fan_kernel<1><<<FNCB, H_DIM, 0, stream>>>(x, alpha, part, nullptr, out);
    }
    reduce_kernel<<<32, H_DIM, 0, stream>>>(part, part2);
    if (half_path) {
        epilogue_kernel<true><<<ENCB, 256, 0, stream>>>(x, stash16, part2, gamma, beta, out);
    } else {
        epilogue_kernel<false><<<ENCB, 256, 0, stream>>>(x, out, part2, gamma, beta, out);
    }
}

// Round 7
// 343.488 us; speedup vs baseline: 1.0689x; 1.0689x over previous
//
#include <hip/hip_runtime.h>
#include <hip/hip_fp16.h>

#define T_DIM 2048
#define H_DIM 256
#define B_DIM 64

/* fan kernel chunking */
#define FCH 64                /* t per fan block */
#define FNCH (T_DIM / FCH)    /* 32 chunks per batch row */
#define FNCB (B_DIM * FNCH)   /* 2048 fan blocks */

/* epilogue chunking */
#define ECH 64
#define ENCH (T_DIM / ECH)    /* 32 */
#define ENCB (B_DIM * ENCH)   /* 2048 */

#define EPS_F 1e-4f
#define R1C (1.0f / 1.0001f)
#define R2C (1.0f / 2.0001f)

#define GLB(p) ((const __attribute__((address_space(1))) void*)(p))
#define LDSP(p) ((__attribute__((address_space(3))) void*)(p))

// mu and inv-sd (= 1/max(sqrt(var),EPS)) from window sums.
__device__ __forceinline__ void win_stats(float s1, float s2, float inv_w, float inv_wm1,
                                          float& mu, float& isd) {
    mu = s1 * inv_w;
    float var = fmaxf((s2 - s1 * s1 * inv_w) * inv_wm1, 0.0f);
    // 1/max(sqrt(var),1e-4) == min(rsqrt(var), 1e4); rsqrt(0)=inf -> 1e4. Matches ref.
    isd = fminf(rsqrtf(var), 1e4f);
}

// FAN kernel, LDS-staged (R5): x rows stream through a 32-row LDS ring via
// global_load_lds (zero VGPR cost). Inner loop reads v and ALL taps (5/10/20)
// from LDS -> no global loads, no register delay-line (R1-R4 showed the
// register/VMEM-latency tradeoff is a closed loop at ~100us). HBM latency sits
// at the per-group barrier drain, hidden by 5 blocks/CU (LDS 32KB-limited).
// MODE 0: stash fan as __half2 t-pairs (layout [t/2][h][2]); MODE 1: fp32 to d_out.
template <int MODE, bool FIRST>
__device__ __forceinline__ void run_main(
    float (*xs)[H_DIM], const float* __restrict__ xb, int t0, int h, int wave, int lane,
    __half2* __restrict__ s2bh, float* __restrict__ s32bh,
    float al0, float al1, float al2, float& ls1, float& ls2,
    float mu5i, float isd5i, float mu10i, float isd10i, float mu20i, float isd20i) {

    float s1_5 = 0.f, s2_5 = 0.f, s1_10 = 0.f, s2_10 = 0.f, s1_20 = 0.f, s2_20 = 0.f;

    if (!FIRST) {
        // Warm-up sums over rows [t0-20, t0) -- already staged in LDS slots.
#pragma unroll
        for (int j = 1; j <= 20; ++j) {
            float v = xs[(-j) & 31][h];
            s1_20 += v; s2_20 += v * v;
            if (j <= 10) { s1_10 += v; s2_10 += v * v; }
            if (j <= 5)  { s1_5  += v; s2_5  += v * v; }
        }
    }

    float fprev = 0.0f;
    for (int g = 0; g < 8; ++g) {
#pragma unroll
        for (int j = 0; j < 8; ++j) {
            const int rl = 8 * g + j;        // local row (g uniform runtime, j c-t)
            const int t = t0 + rl;
            const float v = xs[rl & 31][h];

            s1_5  += v; s2_5  += v * v;
            s1_10 += v; s2_10 += v * v;
            s1_20 += v; s2_20 += v * v;
            if (!FIRST || rl >= 5)  { float o = xs[(rl - 5)  & 31][h]; s1_5  -= o; s2_5  -= o * o; }
            if (!FIRST || rl >= 10) { float o = xs[(rl - 10) & 31][h]; s1_10 -= o; s2_10 -= o * o; }
            if (!FIRST || rl >= 20) { float o = xs[(rl - 20) & 31][h]; s1_20 -= o; s2_20 -= o * o; }

            float mu, isd, fan = 0.0f;
            if (!FIRST || rl >= 4)  win_stats(s1_5,  s2_5,  0.2f,  0.25f,      mu, isd);
            else { mu = mu5i;  isd = isd5i; }
            fan += (v - mu) * isd * al0;
            if (!FIRST || rl >= 9)  win_stats(s1_10, s2_10, 0.1f,  1.f / 9.f,  mu, isd);
            else { mu = mu10i; isd = isd10i; }
            fan += (v - mu) * isd * al1;
            if (!FIRST || rl >= 19) win_stats(s1_20, s2_20, 0.05f, 1.f / 19.f, mu, isd);
            else { mu = mu20i; isd = isd20i; }
            fan += (v - mu) * isd * al2;

            ls1 += fan; ls2 += fan * fan;
            if (MODE == 0) {
                if (j & 1) s2bh[(size_t)(t >> 1) * H_DIM] =
                               __halves2half2(__float2half(fprev), __float2half(fan));
                else       fprev = fan;
            } else {
                s32bh[t * H_DIM] = fan;
            }
        }
        if (g < 7) {
            __syncthreads();   // B1: all waves done reading slots we'll overwrite
            // Stage next 8 rows (local rl = 8g+12 .. 8g+19), 2 per wave.
            const int rl0 = 8 * g + 12 + 2 * wave;
#pragma unroll
            for (int j = 0; j < 2; ++j) {
                const int rl = rl0 + j;
                if (rl < FCH) {   // never stage past chunk end (OOB guard for c=31)
                    __builtin_amdgcn_global_load_lds(
                        GLB(xb + (size_t)(t0 + rl) * H_DIM + lane * 4),
                        LDSP(&xs[rl & 31][0]), 16, 0, 0);
                }
            }
            __syncthreads();   // B2: drain (compiler emits vmcnt(0)) -> rows visible
        }
    }
}

template <int MODE>
__global__ __launch_bounds__(256)
void fan_kernel(const float* __restrict__ x, const float* __restrict__ alpha,
                float* __restrict__ part, __half* __restrict__ stash16,
                float* __restrict__ stash32) {
    __shared__ __align__(16) float xs[32][H_DIM];   // 32 KB -> 5 blocks/CU
    // XCD-aware bijective swizzle (FNCB = 2048 = 8*256).
    const int blk = (blockIdx.x & 7) * (FNCB / 8) + (blockIdx.x >> 3);
    const int b = blk / FNCH;
    const int c = blk % FNCH;
    const int h = threadIdx.x;
    const int wave = h >> 6;
    const int lane = h & 63;
    const int t0 = c * FCH;
    const size_t base = (size_t)b * T_DIM * H_DIM;
    const float* xb = x + base;                      // row r at xb + r*H_DIM
    __half2* s2bh = (MODE == 0)
        ? (__half2*)stash16 + (size_t)b * (T_DIM / 2) * H_DIM + h : nullptr;
    float* s32bh = (MODE == 1) ? stash32 + base + h : nullptr;

    // Prologue stage: local rows [-20, 12), 8 per wave; skip r<0 (c==0).
    {
        const int rl0 = -20 + 8 * wave;
#pragma unroll
        for (int j = 0; j < 8; ++j) {
            const int rl = rl0 + j;
            if (t0 + rl >= 0) {
                __builtin_amdgcn_global_load_lds(
                    GLB(xb + (size_t)(t0 + rl) * H_DIM + lane * 4),
                    LDSP(&xs[rl & 31][0]), 16, 0, 0);
            }
        }
    }

    // softmax over alpha[h][0..2] (independent of staging; overlaps it)
    const float a0 = alpha[h * 3 + 0], a1 = alpha[h * 3 + 1], a2 = alpha[h * 3 + 2];
    const float mx = fmaxf(a0, fmaxf(a1, a2));
    const float e0 = __expf(a0 - mx), e1 = __expf(a1 - mx), e2 = __expf(a2 - mx);
    const float einv = 1.0f / (e0 + e1 + e2);
    const float al0 = e0 * einv, al1 = e1 * einv, al2 = e2 * einv;

    float ls1 = 0.0f, ls2 = 0.0f;

    if (c == 0) {
        // Edge stats from global (20 loads, prologue-only path).
        float mu5i, isd5i, mu10i, isd10i, mu20i, isd20i;
        float c1 = 0.f, c2 = 0.f;
#pragma unroll
        for (int j = 0; j < 20; ++j) {
            float v = xb[j * H_DIM + h];
            c1 += v; c2 += v * v;
            if (j == 4)  win_stats(c1, c2, 0.2f,  0.25f,      mu5i,  isd5i);
            if (j == 9)  win_stats(c1, c2, 0.1f,  1.f / 9.f,  mu10i, isd10i);
            if (j == 19) win_stats(c1, c2, 0.05f, 1.f / 19.f, mu20i, isd20i);
        }
        __syncthreads();   // prologue rows visible
        run_main<MODE, true>(xs, xb, t0, h, wave, lane, s2bh, s32bh,
                             al0, al1, al2, ls1, ls2,
                             mu5i, isd5i, mu10i, isd10i, mu20i, isd20i);
    } else {
        __syncthreads();   // prologue rows visible
        run_main<MODE, false>(xs, xb, t0, h, wave, lane, s2bh, s32bh,
                              al0, al1, al2, ls1, ls2,
                              0.f, 0.f, 0.f, 0.f, 0.f, 0.f);
    }

    part[(0 * FNCB + blk) * H_DIM + h] = ls1;
    part[(1 * FNCB + blk) * H_DIM + h] = ls2;
}

// 32 blocks: (slice k = blk>>4, 1/16th g = blk&15). NO atomics: writes partial
// sums to part2[64][256]. Epilogue finishes the reduction.
__global__ __launch_bounds__(256)
void reduce_kernel(const float* __restrict__ part, float* __restrict__ part2) {
    const int h = threadIdx.x;
    const int k = blockIdx.x >> 4;     // slice 0/1
    const int g = blockIdx.x & 15;
    float a1 = 0.f, a2 = 0.f;
    for (int i = 0; i < FNCB / 16; ++i) {
        const int blk = g * (FNCB / 16) + i;
        const int c = blk % FNCH;
        const bool member = (k == 0) ? (c < 24) : (c >= 16);
        if (member) {
            a1 += part[(0 * FNCB + blk) * H_DIM + h];
            a2 += part[(1 * FNCB + blk) * H_DIM + h];
        }
    }
    part2[((2 * k + 0) * 16 + g) * H_DIM + h] = a1;
    part2[((2 * k + 1) * 16 + g) * H_DIM + h] = a2;
}

// Epilogue with inlined finalize: each block sums the 16 partials per category
// (L2-hot), computes per-h affine coefs into LDS, then streams out = x + fan*A + B.
template <bool HALF>
__global__ __launch_bounds__(256)
void epilogue_kernel(const float* __restrict__ x, const void* __restrict__ fanp,
                     const float* __restrict__ part2, const float* __restrict__ gamma,
                     const float* __restrict__ beta, float* __restrict__ out) {
    __shared__ __align__(16) float cf[4][H_DIM];
    const int tid = threadIdx.x;

    // ---- inline finalize (per-h, thread tid = h) ----
    {
        float S10 = 0.f, S20 = 0.f, S11 = 0.f, S21 = 0.f;
#pragma unroll
        for (int g = 0; g < 16; ++g) {
            S10 += part2[(0 * 16 + g) * H_DIM + tid];
            S20 += part2[(1 * 16 + g) * H_DIM + tid];
            S11 += part2[(2 * 16 + g) * H_DIM + tid];
            S21 += part2[(3 * 16 + g) * H_DIM + tid];
        }
        const float N0 = 64.0f * 1536.0f, N1 = 64.0f * 1024.0f;
        float mu0 = S10 / N0;
        float v0 = fmaxf((S20 - S10 * S10 / N0) / (N0 - 1.0f), 0.0f);
        float isd0 = 1.0f / fmaxf(sqrtf(v0), EPS_F);
        float mu1 = S11 / N1;
        float v1 = fmaxf((S21 - S11 * S11 / N1) / (N1 - 1.0f), 0.0f);
        float isd1 = 1.0f / fmaxf(sqrtf(v1), EPS_F);
        float A0 = isd0 * gamma[0 * H_DIM + tid];
        float A1 = isd1 * gamma[1 * H_DIM + tid];
        cf[0][tid] = A0;
        cf[1][tid] = beta[0 * H_DIM + tid] - mu0 * A0;
        cf[2][tid] = A1;
        cf[3][tid] = beta[1 * H_DIM + tid] - mu1 * A1;
    }
    __syncthreads();

    const int blk = blockIdx.x;
    const int b = blk / ENCH;
    const int c = blk % ENCH;
    const int wave = tid >> 6;
    const int lane = tid & 63;
    const int h4 = lane * 4;

    float4 A0 = *(const float4*)&cf[0][h4];
    float4 B0 = *(const float4*)&cf[1][h4];
    float4 A1 = *(const float4*)&cf[2][h4];
    float4 B1 = *(const float4*)&cf[3][h4];
    float4 A, Bv;
    if (c < 16) {
        A  = make_float4(A0.x * R1C, A0.y * R1C, A0.z * R1C, A0.w * R1C);
        Bv = make_float4(B0.x * R1C, B0.y * R1C, B0.z * R1C, B0.w * R1C);
    } else if (c >= 24) {
        A  = make_float4(A1.x * R1C, A1.y * R1C, A1.z * R1C, A1.w * R1C);
        Bv = make_float4(B1.x * R1C, B1.y * R1C, B1.z * R1C, B1.w * R1C);
    } else {
        A  = make_float4((A0.x + A1.x) * R2C, (A0.y + A1.y) * R2C, (A0.z + A1.z) * R2C, (A0.w + A1.w) * R2C);
        Bv = make_float4((B0.x + B1.x) * R2C, (B0.y + B1.y) * R2C, (B0.z + B1.z) * R2C, (B0.w + B1.w) * R2C);
    }

    const int tbase = c * ECH + wave * 16;
    if (HALF) {
        const __half2* s2 = (const __half2*)fanp + (size_t)b * (T_DIM / 2) * H_DIM + h4;
#pragma unroll 2
        for (int p = 0; p < 8; ++p) {
            const int t = tbase + 2 * p;
            const size_t xi = ((size_t)b * T_DIM + t) * H_DIM + h4;
            float4 x0 = *(const float4*)&x[xi];
            float4 x1 = *(const float4*)&x[xi + H_DIM];
            float4 sv = *(const float4*)(s2 + (size_t)(t >> 1) * H_DIM);
            __half2 q0 = *reinterpret_cast<const __half2*>(&sv.x);
            __half2 q1 = *reinterpret_cast<const __half2*>(&sv.y);
            __half2 q2 = *reinterpret_cast<const __half2*>(&sv.z);
            __half2 q3 = *reinterpret_cast<const __half2*>(&sv.w);
            float4 o0, o1;
            o0.x = x0.x + fmaf(__low2float(q0),  A.x, Bv.x);
            o0.y = x0.y + fmaf(__low2float(q1),  A.y, Bv.y);
            o0.z = x0.z + fmaf(__low2float(q2),  A.z, Bv.z);
            o0.w = x0.w + fmaf(__low2float(q3),  A.w, Bv.w);
            o1.x = x1.x + fmaf(__high2float(q0), A.x, Bv.x);
            o1.y = x1.y + fmaf(__high2float(q1), A.y, Bv.y);
            o1.z = x1.z + fmaf(__high2float(q2), A.z, Bv.z);
            o1.w = x1.w + fmaf(__high2float(q3), A.w, Bv.w);
            *(float4*)&out[xi] = o0;
            *(float4*)&out[xi + H_DIM] = o1;
        }
    } else {
#pragma unroll 4
        for (int i = 0; i < 16; ++i) {
            const size_t idx = ((size_t)b * T_DIM + tbase + i) * H_DIM + h4;
            float4 xv = *(const float4*)&x[idx];
            float4 fv = *(const float4*)&((const float*)fanp)[idx];
            float4 o;
            o.x = xv.x + fmaf(fv.x, A.x, Bv.x);
            o.y = xv.y + fmaf(fv.y, A.y, Bv.y);
            o.z = xv.z + fmaf(fv.z, A.z, Bv.z);
            o.w = xv.w + fmaf(fv.w, A.w, Bv.w);
            *(float4*)&out[idx] = o;
        }
    }
}

extern "C" void kernel_launch(void* const* d_in, const int* in_sizes, int n_in,
                              void* d_out, int out_size, void* d_ws, size_t ws_size,
                              hipStream_t stream) {
    const float* x     = (const float*)d_in[0];
    const float* alpha = (const float*)d_in[1];
    const float* gamma = (const float*)d_in[2];
    const float* beta  = (const float*)d_in[3];
    float* out  = (float*)d_out;

    float* part  = (float*)d_ws;                         // 2*FNCB*H floats = 4 MB
    float* part2 = part + 2 * FNCB * H_DIM;              // 64*H floats = 64 KB
    __half* stash16 = (__half*)(part2 + 64 * H_DIM);     // B*T*H halves = 67 MB
    const size_t need = (size_t)(2 * FNCB * H_DIM + 64 * H_DIM) * 4
                      + (size_t)B_DIM * T_DIM * H_DIM * 2;
    const bool half_path = (ws_size >= need);            // constant per process -> graph-safe

    if (half_path) {
        fan_kernel<0><<<FNCB, H_DIM, 0, stream>>>(x, alpha, part, stash16, nullptr);
    } else {
        // Fallback: stash fp32 fan in d_out; epilogue overwrites it in place.
        fan_kernel<1><<<FNCB, H_DIM, 0, stream>>>(x, alpha, part, nullptr, out);
    }
    reduce_kernel<<<32, H_DIM, 0, stream>>>(part, part2);
    if (half_path) {
        epilogue_kernel<true><<<ENCB, 256, 0, stream>>>(x, stash16, part2, gamma, beta, out);
    } else {
        epilogue_kernel<false><<<ENCB, 256, 0, stream>>>(x, out, part2, gamma, beta, out);
    }
}

// Round 8
// 341.959 us; speedup vs baseline: 1.0737x; 1.0045x over previous
//
#include <hip/hip_runtime.h>
#include <hip/hip_fp16.h>

#define T_DIM 2048
#define H_DIM 256
#define B_DIM 64

/* fan kernel chunking */
#define FCH 64                /* t per fan block */
#define FNCH (T_DIM / FCH)    /* 32 chunks per batch row */
#define FNCB (B_DIM * FNCH)   /* 2048 fan blocks */

/* epilogue chunking */
#define ECH 64
#define ENCH (T_DIM / ECH)    /* 32 */
#define ENCB (B_DIM * ENCH)   /* 2048 */

#define EPS_F 1e-4f
#define R1C (1.0f / 1.0001f)
#define R2C (1.0f / 2.0001f)

#define GLB(p) ((const __attribute__((address_space(1))) void*)(p))
#define LDSP(p) ((__attribute__((address_space(3))) void*)(p))

// mu and inv-sd (= 1/max(sqrt(var),EPS)) from window sums.
__device__ __forceinline__ void win_stats(float s1, float s2, float inv_w, float inv_wm1,
                                          float& mu, float& isd) {
    mu = s1 * inv_w;
    float var = fmaxf((s2 - s1 * s1 * inv_w) * inv_wm1, 0.0f);
    // 1/max(sqrt(var),1e-4) == min(rsqrt(var), 1e4); rsqrt(0)=inf -> 1e4. Matches ref.
    isd = fminf(rsqrtf(var), 1e4f);
}

// FAN kernel, R8: 40-row LDS ring + counted-vmcnt pipeline.
// R7 lesson: 32-row ring forces issue->drain with ZERO latency window (rows
// staged at end of g are needed at g+1; vmcnt(0) right after issue exposes
// ~900cy HBM latency every 8 rows -> VALUBusy stuck at 59%).
// R8: ring 40 (slot(8g+j) = 8*(g%5)+j). Issue rows 8(g+2) at end of g ->
// overwrites rows 8g-24..8g-17, all older than oldest live tap (8g-12): SAFE.
// Drain is s_waitcnt vmcnt(2): waits only for g+1's rows (issued one full
// group ago). Raw s_barrier (NOT __syncthreads: that re-inserts vmcnt(0) --
// the m97 stall). vmcnt(2) is sound: vmcnt retires oldest-first, so <=2
// outstanding == this group's 2 newest loads; older loads AND stash stores
// are then retired.
template <int MODE, bool FIRST>
__device__ __forceinline__ void run_main(
    float* __restrict__ xs, const float* __restrict__ xb, int t0, int h, int wave, int lane,
    __half2* __restrict__ s2bh, float* __restrict__ s32bh,
    float al0, float al1, float al2, float& ls1, float& ls2,
    float mu5i, float isd5i, float mu10i, float isd10i, float mu20i, float isd20i) {

    // Drain prologue part-1 (rows -20..7) and make visible to all waves.
    asm volatile("s_waitcnt vmcnt(0)" ::: "memory");
    __builtin_amdgcn_s_barrier();

    // Part-2 issue: rows 8..15 (2/wave) -> slots 8..15. Consumed at g=1;
    // drained by the counted vmcnt at end of g=0 (one-group latency window).
    {
        float* d = xs + (8 + 2 * wave) * H_DIM;
        __builtin_amdgcn_global_load_lds(
            GLB(xb + (size_t)(t0 + 8 + 2 * wave) * H_DIM + lane * 4), LDSP(d), 16, 0, 0);
        __builtin_amdgcn_global_load_lds(
            GLB(xb + (size_t)(t0 + 9 + 2 * wave) * H_DIM + lane * 4), LDSP(d + H_DIM), 16, 0, 0);
    }

    float s1_5 = 0.f, s2_5 = 0.f, s1_10 = 0.f, s2_10 = 0.f, s1_20 = 0.f, s2_20 = 0.f;

    if (!FIRST) {
        // Warm-up sums over rows [t0-20, t0): row -j sits in slot 40-j.
#pragma unroll
        for (int j = 1; j <= 20; ++j) {
            float v = xs[(40 - j) * H_DIM + h];
            s1_20 += v; s2_20 += v * v;
            if (j <= 10) { s1_10 += v; s2_10 += v * v; }
            if (j <= 5)  { s1_5  += v; s2_5  += v * v; }
        }
    }

    // Rotating slot-group indices: gc=g%5, gp1=(g-1)%5, gp2=(g-2)%5, gp3=(g-3)%5.
    // Note (g+2)%5 == (g-3)%5, so gp3 is ALSO the staging target group.
    int gc = 0, gp1 = 4, gp2 = 3, gp3 = 2;

    float fprev = 0.0f;
    for (int g = 0; g < 8; ++g) {
        const float* bc = xs + gc  * (8 * H_DIM) + h;
        const float* b1 = xs + gp1 * (8 * H_DIM) + h;
        const float* b2 = xs + gp2 * (8 * H_DIM) + h;
        const float* b3 = xs + gp3 * (8 * H_DIM) + h;
#pragma unroll
        for (int j = 0; j < 8; ++j) {
            const int rl = 8 * g + j;
            const int t = t0 + rl;
            const float v = bc[j * H_DIM];
            // Taps via compile-time slot selection (j is unrolled const):
            const float o5  = (j >= 5) ? bc[(j - 5) * H_DIM] : b1[(j + 3) * H_DIM];
            const float o10 = (j >= 2) ? b1[(j - 2) * H_DIM] : b2[(j + 6) * H_DIM];
            const float o20 = (j >= 4) ? b2[(j - 4) * H_DIM] : b3[(j + 4) * H_DIM];

            s1_5  += v; s2_5  += v * v;
            s1_10 += v; s2_10 += v * v;
            s1_20 += v; s2_20 += v * v;
            if (!FIRST || rl >= 5)  { s1_5  -= o5;  s2_5  -= o5  * o5;  }
            if (!FIRST || rl >= 10) { s1_10 -= o10; s2_10 -= o10 * o10; }
            if (!FIRST || rl >= 20) { s1_20 -= o20; s2_20 -= o20 * o20; }

            float mu, isd, fan = 0.0f;
            if (!FIRST || rl >= 4)  win_stats(s1_5,  s2_5,  0.2f,  0.25f,      mu, isd);
            else { mu = mu5i;  isd = isd5i; }
            fan += (v - mu) * isd * al0;
            if (!FIRST || rl >= 9)  win_stats(s1_10, s2_10, 0.1f,  1.f / 9.f,  mu, isd);
            else { mu = mu10i; isd = isd10i; }
            fan += (v - mu) * isd * al1;
            if (!FIRST || rl >= 19) win_stats(s1_20, s2_20, 0.05f, 1.f / 19.f, mu, isd);
            else { mu = mu20i; isd = isd20i; }
            fan += (v - mu) * isd * al2;

            ls1 += fan; ls2 += fan * fan;
            if (MODE == 0) {
                if (j & 1) s2bh[(size_t)(t >> 1) * H_DIM] =
                               __halves2half2(__float2half(fprev), __float2half(fan));
                else       fprev = fan;
            } else {
                s32bh[t * H_DIM] = fan;
            }
        }
        if (g < 7) {
            asm volatile("" ::: "memory");     // keep tap reads above the overwrite
            __builtin_amdgcn_s_barrier();      // B1: all waves done with group g
            const int rn = 8 * (g + 2) + 2 * wave;
            if (rn < FCH) {                    // g<6: stage rows for group g+2
                float* d = xs + (gp3 * 8 + 2 * wave) * H_DIM;
                __builtin_amdgcn_global_load_lds(
                    GLB(xb + (size_t)(t0 + rn) * H_DIM + lane * 4), LDSP(d), 16, 0, 0);
                __builtin_amdgcn_global_load_lds(
                    GLB(xb + (size_t)(t0 + rn + 1) * H_DIM + lane * 4), LDSP(d + H_DIM), 16, 0, 0);
                asm volatile("s_waitcnt vmcnt(2)" ::: "memory");  // g+1's rows done
            } else {
                asm volatile("s_waitcnt vmcnt(0)" ::: "memory");  // g=6: drain for g=7
            }
            __builtin_amdgcn_s_barrier();      // B2: g+1's rows visible to all
            gp3 = gp2; gp2 = gp1; gp1 = gc; gc = (gc == 4) ? 0 : gc + 1;
        }
    }
}

template <int MODE>
__global__ __launch_bounds__(256)
void fan_kernel(const float* __restrict__ x, const float* __restrict__ alpha,
                float* __restrict__ part, __half* __restrict__ stash16,
                float* __restrict__ stash32) {
    __shared__ __align__(16) float xs[40 * H_DIM];   // 40 KB -> 4 blocks/CU
    // XCD-aware bijective swizzle (FNCB = 2048 = 8*256).
    const int blk = (blockIdx.x & 7) * (FNCB / 8) + (blockIdx.x >> 3);
    const int b = blk / FNCH;
    const int c = blk % FNCH;
    const int h = threadIdx.x;
    const int wave = h >> 6;
    const int lane = h & 63;
    const int t0 = c * FCH;
    const size_t base = (size_t)b * T_DIM * H_DIM;
    const float* xb = x + base;                      // row r at xb + r*H_DIM
    __half2* s2bh = (MODE == 0)
        ? (__half2*)stash16 + (size_t)b * (T_DIM / 2) * H_DIM + h : nullptr;
    float* s32bh = (MODE == 1) ? stash32 + base + h : nullptr;

    // Prologue part-1: rows -20..7 (28 rows, 7/wave); row r<0 -> slot r+40.
    {
        const int r0 = -20 + 7 * wave;
#pragma unroll
        for (int j = 0; j < 7; ++j) {
            const int r = r0 + j;
            if (t0 + r >= 0) {
                const int sl = (r < 0) ? r + 40 : r;
                __builtin_amdgcn_global_load_lds(
                    GLB(xb + (size_t)(t0 + r) * H_DIM + lane * 4),
                    LDSP(xs + sl * H_DIM), 16, 0, 0);
            }
        }
    }

    // softmax over alpha[h][0..2] (independent of staging; overlaps it)
    const float a0 = alpha[h * 3 + 0], a1 = alpha[h * 3 + 1], a2 = alpha[h * 3 + 2];
    const float mx = fmaxf(a0, fmaxf(a1, a2));
    const float e0 = __expf(a0 - mx), e1 = __expf(a1 - mx), e2 = __expf(a2 - mx);
    const float einv = 1.0f / (e0 + e1 + e2);
    const float al0 = e0 * einv, al1 = e1 * einv, al2 = e2 * einv;

    float ls1 = 0.0f, ls2 = 0.0f;

    if (c == 0) {
        // Edge stats from global (rows 0..19; overlaps the in-flight DMA, both read x).
        float mu5i, isd5i, mu10i, isd10i, mu20i, isd20i;
        float c1 = 0.f, c2 = 0.f;
#pragma unroll
        for (int j = 0; j < 20; ++j) {
            float v = xb[j * H_DIM + h];
            c1 += v; c2 += v * v;
            if (j == 4)  win_stats(c1, c2, 0.2f,  0.25f,      mu5i,  isd5i);
            if (j == 9)  win_stats(c1, c2, 0.1f,  1.f / 9.f,  mu10i, isd10i);
            if (j == 19) win_stats(c1, c2, 0.05f, 1.f / 19.f, mu20i, isd20i);
        }
        run_main<MODE, true>(xs, xb, t0, h, wave, lane, s2bh, s32bh,
                             al0, al1, al2, ls1, ls2,
                             mu5i, isd5i, mu10i, isd10i, mu20i, isd20i);
    } else {
        run_main<MODE, false>(xs, xb, t0, h, wave, lane, s2bh, s32bh,
                              al0, al1, al2, ls1, ls2,
                              0.f, 0.f, 0.f, 0.f, 0.f, 0.f);
    }

    part[(0 * FNCB + blk) * H_DIM + h] = ls1;
    part[(1 * FNCB + blk) * H_DIM + h] = ls2;
}

// 32 blocks: (slice k = blk>>4, 1/16th g = blk&15). NO atomics: writes partial
// sums to part2[64][256]. Epilogue finishes the reduction.
__global__ __launch_bounds__(256)
void reduce_kernel(const float* __restrict__ part, float* __restrict__ part2) {
    const int h = threadIdx.x;
    const int k = blockIdx.x >> 4;     // slice 0/1
    const int g = blockIdx.x & 15;
    float a1 = 0.f, a2 = 0.f;
    for (int i = 0; i < FNCB / 16; ++i) {
        const int blk = g * (FNCB / 16) + i;
        const int c = blk % FNCH;
        const bool member = (k == 0) ? (c < 24) : (c >= 16);
        if (member) {
            a1 += part[(0 * FNCB + blk) * H_DIM + h];
            a2 += part[(1 * FNCB + blk) * H_DIM + h];
        }
    }
    part2[((2 * k + 0) * 16 + g) * H_DIM + h] = a1;
    part2[((2 * k + 1) * 16 + g) * H_DIM + h] = a2;
}

// Epilogue with inlined finalize: each block sums the 16 partials per category
// (L2-hot), computes per-h affine coefs into LDS, then streams out = x + fan*A + B.
template <bool HALF>
__global__ __launch_bounds__(256)
void epilogue_kernel(const float* __restrict__ x, const void* __restrict__ fanp,
                     const float* __restrict__ part2, const float* __restrict__ gamma,
                     const float* __restrict__ beta, float* __restrict__ out) {
    __shared__ __align__(16) float cf[4][H_DIM];
    const int tid = threadIdx.x;

    // ---- inline finalize (per-h, thread tid = h) ----
    {
        float S10 = 0.f, S20 = 0.f, S11 = 0.f, S21 = 0.f;
#pragma unroll
        for (int g = 0; g < 16; ++g) {
            S10 += part2[(0 * 16 + g) * H_DIM + tid];
            S20 += part2[(1 * 16 + g) * H_DIM + tid];
            S11 += part2[(2 * 16 + g) * H_DIM + tid];
            S21 += part2[(3 * 16 + g) * H_DIM + tid];
        }
        const float N0 = 64.0f * 1536.0f, N1 = 64.0f * 1024.0f;
        float mu0 = S10 / N0;
        float v0 = fmaxf((S20 - S10 * S10 / N0) / (N0 - 1.0f), 0.0f);
        float isd0 = 1.0f / fmaxf(sqrtf(v0), EPS_F);
        float mu1 = S11 / N1;
        float v1 = fmaxf((S21 - S11 * S11 / N1) / (N1 - 1.0f), 0.0f);
        float isd1 = 1.0f / fmaxf(sqrtf(v1), EPS_F);
        float A0 = isd0 * gamma[0 * H_DIM + tid];
        float A1 = isd1 * gamma[1 * H_DIM + tid];
        cf[0][tid] = A0;
        cf[1][tid] = beta[0 * H_DIM + tid] - mu0 * A0;
        cf[2][tid] = A1;
        cf[3][tid] = beta[1 * H_DIM + tid] - mu1 * A1;
    }
    __syncthreads();

    const int blk = blockIdx.x;
    const int b = blk / ENCH;
    const int c = blk % ENCH;
    const int wave = tid >> 6;
    const int lane = tid & 63;
    const int h4 = lane * 4;

    float4 A0 = *(const float4*)&cf[0][h4];
    float4 B0 = *(const float4*)&cf[1][h4];
    float4 A1 = *(const float4*)&cf[2][h4];
    float4 B1 = *(const float4*)&cf[3][h4];
    float4 A, Bv;
    if (c < 16) {
        A  = make_float4(A0.x * R1C, A0.y * R1C, A0.z * R1C, A0.w * R1C);
        Bv = make_float4(B0.x * R1C, B0.y * R1C, B0.z * R1C, B0.w * R1C);
    } else if (c >= 24) {
        A  = make_float4(A1.x * R1C, A1.y * R1C, A1.z * R1C, A1.w * R1C);
        Bv = make_float4(B1.x * R1C, B1.y * R1C, B1.z * R1C, B1.w * R1C);
    } else {
        A  = make_float4((A0.x + A1.x) * R2C, (A0.y + A1.y) * R2C, (A0.z + A1.z) * R2C, (A0.w + A1.w) * R2C);
        Bv = make_float4((B0.x + B1.x) * R2C, (B0.y + B1.y) * R2C, (B0.z + B1.z) * R2C, (B0.w + B1.w) * R2C);
    }

    const int tbase = c * ECH + wave * 16;
    if (HALF) {
        const __half2* s2 = (const __half2*)fanp + (size_t)b * (T_DIM / 2) * H_DIM + h4;
#pragma unroll 2
        for (int p = 0; p < 8; ++p) {
            const int t = tbase + 2 * p;
            const size_t xi = ((size_t)b * T_DIM + t) * H_DIM + h4;
            float4 x0 = *(const float4*)&x[xi];
            float4 x1 = *(const float4*)&x[xi + H_DIM];
            float4 sv = *(const float4*)(s2 + (size_t)(t >> 1) * H_DIM);
            __half2 q0 = *reinterpret_cast<const __half2*>(&sv.x);
            __half2 q1 = *reinterpret_cast<const __half2*>(&sv.y);
            __half2 q2 = *reinterpret_cast<const __half2*>(&sv.z);
            __half2 q3 = *reinterpret_cast<const __half2*>(&sv.w);
            float4 o0, o1;
            o0.x = x0.x + fmaf(__low2float(q0),  A.x, Bv.x);
            o0.y = x0.y + fmaf(__low2float(q1),  A.y, Bv.y);
            o0.z = x0.z + fmaf(__low2float(q2),  A.z, Bv.z);
            o0.w = x0.w + fmaf(__low2float(q3),  A.w, Bv.w);
            o1.x = x1.x + fmaf(__high2float(q0), A.x, Bv.x);
            o1.y = x1.y + fmaf(__high2float(q1), A.y, Bv.y);
            o1.z = x1.z + fmaf(__high2float(q2), A.z, Bv.z);
            o1.w = x1.w + fmaf(__high2float(q3), A.w, Bv.w);
            *(float4*)&out[xi] = o0;
            *(float4*)&out[xi + H_DIM] = o1;
        }
    } else {
#pragma unroll 4
        for (int i = 0; i < 16; ++i) {
            const size_t idx = ((size_t)b * T_DIM + tbase + i) * H_DIM + h4;
            float4 xv = *(const float4*)&x[idx];
            float4 fv = *(const float4*)&((const float*)fanp)[idx];
            float4 o;
            o.x = xv.x + fmaf(fv.x, A.x, Bv.x);
            o.y = xv.y + fmaf(fv.y, A.y, Bv.y);
            o.z = xv.z + fmaf(fv.z, A.z, Bv.z);
            o.w = xv.w + fmaf(fv.w, A.w, Bv.w);
            *(float4*)&out[idx] = o;
        }
    }
}

extern "C" void kernel_launch(void* const* d_in, const int* in_sizes, int n_in,
                              void* d_out, int out_size, void* d_ws, size_t ws_size,
                              hipStream_t stream) {
    const float* x     = (const float*)d_in[0];
    const float* alpha = (const float*)d_in[1];
    const float* gamma = (const float*)d_in[2];
    const float* beta  = (const float*)d_in[3];
    float* out  = (float*)d_out;

    float* part  = (float*)d_ws;                         // 2*FNCB*H floats = 4 MB
    float* part2 = part + 2 * FNCB * H_DIM;              // 64*H floats = 64 KB
    __half* stash16 = (__half*)(part2 + 64 * H_DIM);     // B*T*H halves = 67 MB
    const size_t need = (size_t)(2 * FNCB * H_DIM + 64 * H_DIM) * 4
                      + (size_t)B_DIM * T_DIM * H_DIM * 2;
    const bool half_path = (ws_size >= need);            // constant per process -> graph-safe

    if (half_path) {
        fan_kernel<0><<<FNCB, H_DIM, 0, stream>>>(x, alpha, part, stash16, nullptr);
    } else {
        // Fallback: stash fp32 fan in d_out; epilogue overwrites it in place.
        fan_kernel<1><<<FNCB, H_DIM, 0, stream>>>(x, alpha, part, nullptr, out);
    }
    reduce_kernel<<<32, H_DIM, 0, stream>>>(part, part2);
    if (half_path) {
        epilogue_kernel<true><<<ENCB, 256, 0, stream>>>(x, stash16, part2, gamma, beta, out);
    } else {
        epilogue_kernel<false><<<ENCB, 256, 0, stream>>>(x, out, part2, gamma, beta, out);
    }
}